// Round 7
// baseline (711.226 us; speedup 1.0000x reference)
//
#include <hip/hip_runtime.h>

// Flash-attention fwd, B=4 H=16 S=2048 D=128, fp32 in/out, bf16 MFMA compute.
// Round 9: the LDS pipe was ~85% saturated (700 LDS-cyc/wave-iter: K/V frags +
// P round-trip + 32 shuffle swizzles) -- occupancy rounds 6/8 couldn't help.
// Restructure to 32x32x16 MFMA with swapped operands (T12/m214 structure):
//   S^T = mfma(K, Q)  -> lane owns q = lane&31; P-row fully in-register
//   softmax: 31 in-lane ops + ONE shfl_xor(32); m/l/alpha are per-lane scalars
//   P -> PV B-frags via 16 v_cvt_pk_bf16_f32 + 8 v_permlane32_swap (no LDS)
//   O^T = mfma(V^T, P^T) -> C col = q = lane&31, rescale is lane-uniform
// LDS/wave-iter: 84 ops -> 34 (32 ds_read_b128 + 2 swizzles), covering 2x the
// q rows. K image swizzle widened to ^(row&15) for conflict-free 32-row reads.
// BQ=128 (4 waves x 32q), 48KB LDS -> 3 blocks/CU.

#define S_LEN 2048
#define HD 128
#define BK 64
#define NT (S_LEN / BK)          // 32
#define TILE_SH (BK * HD)        // 8192 shorts = 16 KB per staged tile image
#define NBH 64
#define BQ 128

typedef __attribute__((ext_vector_type(8)))  short bf16x8;
typedef __attribute__((ext_vector_type(4)))  float f32x4;
typedef __attribute__((ext_vector_type(16))) float f32x16;
typedef __attribute__((ext_vector_type(4)))  short s16x4;
typedef __attribute__((ext_vector_type(4)))  unsigned int u32x4;

static __device__ __forceinline__ unsigned short f2bf(float f) {
    unsigned int u = __builtin_bit_cast(unsigned int, f);
    u += 0x7fffu + ((u >> 16) & 1u);   // round-to-nearest-even
    return (unsigned short)(u >> 16);
}

// global -> LDS direct DMA, 16B per lane; LDS dest = wave-uniform base + lane*16
static __device__ __forceinline__ void gload16(const short* g, short* l) {
    __builtin_amdgcn_global_load_lds(
        (const __attribute__((address_space(1))) unsigned int*)(const void*)g,
        (__attribute__((address_space(3))) unsigned int*)(void*)l,
        16, 0, 0);
}

// ---------------------------------------------------------------------------
// Prepass: build bf16 tile images in workspace.
//   K image [bh][kt][row 0..63][cb 0..15][8]: phys block cb holds logical
//     block cb^(row&15) of K[row] (8 bf16 each).  (&15: 32-row frag reads)
//   V image [bh][kt][d 0..127][cb 0..7][8]: phys block cb holds
//     V[kt*64 + ((cb^(d&7))*8) .. +8][d].
// ---------------------------------------------------------------------------
__global__ __launch_bounds__(256)
void prep_kernel(const float* __restrict__ kg0, const float* __restrict__ vg0,
                 short* __restrict__ wsk, short* __restrict__ wsv)
{
    const int kt = blockIdx.x;
    const int bh = blockIdx.y;
    const int t  = threadIdx.x;
    if (blockIdx.z == 0) {
        const float* src = kg0 + ((size_t)bh * S_LEN + kt * BK) * HD;
        short* dst = wsk + ((size_t)bh * NT + kt) * TILE_SH;
        #pragma unroll
        for (int i = 0; i < 4; ++i) {
            const int c = t + 256 * i;
            const int row = c >> 4, cb = c & 15;
            const float* s = src + row * HD + ((cb ^ (row & 15)) << 3);
            const f32x4 a = *(const f32x4*)s;
            const f32x4 b = *(const f32x4*)(s + 4);
            bf16x8 o;
            #pragma unroll
            for (int j = 0; j < 4; ++j) {
                o[j]     = (short)f2bf(a[j]);
                o[j + 4] = (short)f2bf(b[j]);
            }
            *(bf16x8*)(dst + (size_t)c * 8) = o;
        }
    } else {
        __shared__ short lv[BK * 136];    // [kk][d] staging for the transpose
        const float* src = vg0 + ((size_t)bh * S_LEN + kt * BK) * HD;
        short* dst = wsv + ((size_t)bh * NT + kt) * TILE_SH;
        #pragma unroll
        for (int p = 0; p < 2; ++p) {
            const int kk = (t >> 3) + p * 32;
            const int d0 = (t & 7) * 16;
            const float* s = src + kk * HD + d0;
            #pragma unroll
            for (int g = 0; g < 2; ++g) {
                const f32x4 a = *(const f32x4*)(s + g * 8);
                const f32x4 b = *(const f32x4*)(s + g * 8 + 4);
                bf16x8 o;
                #pragma unroll
                for (int j = 0; j < 4; ++j) {
                    o[j]     = (short)f2bf(a[j]);
                    o[j + 4] = (short)f2bf(b[j]);
                }
                *(bf16x8*)&lv[kk * 136 + d0 + g * 8] = o;
            }
        }
        __syncthreads();
        #pragma unroll
        for (int i = 0; i < 4; ++i) {
            const int c = t + 256 * i;
            const int d = c >> 3, cb = c & 7;
            const int kk0 = (cb ^ (d & 7)) << 3;
            bf16x8 o;
            #pragma unroll
            for (int j = 0; j < 8; ++j) o[j] = lv[(kk0 + j) * 136 + d];
            *(bf16x8*)(dst + (size_t)c * 8) = o;
        }
    }
}

// ---------------------------------------------------------------------------
// Main kernel: 4 waves x 32 q-rows each, 32x32x16 MFMA, swapped operands.
// 48 KB LDS => 3 blocks/CU.
// ---------------------------------------------------------------------------
__global__ __launch_bounds__(256, 3)
void fattn_ws_kernel(const short* __restrict__ wsk, const short* __restrict__ wsv,
                     const float* __restrict__ qg0, const float* __restrict__ maskg,
                     float* __restrict__ outg0)
{
    __shared__ short k_lds[2][TILE_SH];   // double-buffered K tile image
    __shared__ short v_lds[TILE_SH];      // single-buffered V^T tile image

    const int tid  = threadIdx.x;
    const int wave = tid >> 6;            // 0..3
    const int lane = tid & 63;
    const int l32  = lane & 31;           // this lane's q (within wave tile)
    const int hi   = lane >> 5;           // k-group half

    const int bh = blockIdx.x;            // fast dim: co-resident blocks share K/V
    const int q0 = blockIdx.y * BQ;
    const int qrow_g = q0 + wave * 32 + l32;

    const float* qg   = qg0 + (size_t)bh * S_LEN * HD;
    float*       outg = outg0 + (size_t)bh * S_LEN * HD;
    const short* ktiles = wsk + (size_t)bh * NT * TILE_SH;
    const short* vtiles = wsv + (size_t)bh * NT * TILE_SH;

    const int soff = tid * 8;             // per-thread offset in tile (shorts)
    const int loff = (tid & ~63) * 8;     // wave-uniform LDS offset (shorts)

    // issue K tile 0 immediately (drained by first barrier)
    #pragma unroll
    for (int p = 0; p < 4; ++p)
        gload16(ktiles + p * 2048 + soff, &k_lds[0][p * 2048 + loff]);

    // Q B-frags: n = q = l32, k(d) = ds*16 + hi*8 + j  (held whole kernel)
    bf16x8 qf[8];
    {
        const float* qr = qg + (size_t)qrow_g * HD + hi * 8;
        #pragma unroll
        for (int ds = 0; ds < 8; ++ds) {
            const f32x4 a = *(const f32x4*)(qr + ds * 16);
            const f32x4 b = *(const f32x4*)(qr + ds * 16 + 4);
            #pragma unroll
            for (int j = 0; j < 4; ++j) {
                qf[ds][j]     = (short)f2bf(a[j]);
                qf[ds][j + 4] = (short)f2bf(b[j]);
            }
        }
    }

    float m_run = -3.0e38f, l_run = 0.0f;
    f32x16 oacc[4];                        // O^T: row d = crow(reg,hi), col q = l32
    #pragma unroll
    for (int dt = 0; dt < 4; ++dt)
        #pragma unroll
        for (int r = 0; r < 16; ++r) oacc[dt][r] = 0.0f;

    const float LOG2E  = 1.4426950408889634f;
    const float scale2 = 0.088388347648318447f * LOG2E;  // (1/sqrt(128))*log2e
    const float* mptr = maskg + (size_t)qrow_g * S_LEN + hi * 4;

    // LDS read geometry (swizzles are lane-constant: 32 = 0 mod 16/8)
    const int swK = l32 & 15;
    const int swV = l32 & 7;
    const int kr0 = l32 * 128;            // K tile0 row base (shorts)
    const int kr1 = kr0 + 32 * 128;       // K tile1 row base
    const int vr  = l32 * 64;             // V^T row base within dtile

    for (int kt = 0; kt < NT; ++kt) {
        const short* kcur = k_lds[kt & 1];

        asm volatile("s_waitcnt vmcnt(0)" ::: "memory");  // K[kt] DMA landed
        __syncthreads();

        // issue V[kt]; latency hidden under QK^T + softmax
        #pragma unroll
        for (int p = 0; p < 4; ++p)
            gload16(vtiles + (size_t)kt * TILE_SH + p * 2048 + soff,
                    &v_lds[p * 2048 + loff]);

        // mask gathers (per-lane row q; each 64B line fully consumed) — land
        // during QK^T.  element e of mk_t[m] ~ k = kt*64 + t*32 + 8m + 4hi + e
        f32x4 mk0[4], mk1[4];
        {
            const float* mb = mptr + kt * 64;
            #pragma unroll
            for (int m = 0; m < 4; ++m) {
                mk0[m] = *(const f32x4*)(mb + m * 8);
                mk1[m] = *(const f32x4*)(mb + 32 + m * 8);
            }
        }

        // ---- S^T = K · Q^T  (two 32x32 kv-tiles, K from LDS, Q in regs) ----
        f32x16 sf0, sf1;
        #pragma unroll
        for (int r = 0; r < 16; ++r) { sf0[r] = 0.0f; sf1[r] = 0.0f; }
        __builtin_amdgcn_s_setprio(1);
        #pragma unroll
        for (int ds = 0; ds < 8; ++ds) {
            const bf16x8 kf0 = *(const bf16x8*)
                &kcur[kr0 + (((ds * 2 + hi) ^ swK) << 3)];
            sf0 = __builtin_amdgcn_mfma_f32_32x32x16_bf16(kf0, qf[ds], sf0, 0, 0, 0);
        }
        #pragma unroll
        for (int ds = 0; ds < 8; ++ds) {
            const bf16x8 kf1 = *(const bf16x8*)
                &kcur[kr1 + (((ds * 2 + hi) ^ swK) << 3)];
            sf1 = __builtin_amdgcn_mfma_f32_32x32x16_bf16(kf1, qf[ds], sf1, 0, 0, 0);
        }
        __builtin_amdgcn_s_setprio(0);

        // ---- softmax: row q = l32, fully in-register (log2 domain) ----
        // sv_t[r] ~ k-row = 32t + (r&3) + 8(r>>2) + 4hi
        float sv0[16], sv1[16], mt[16];
        #pragma unroll
        for (int r = 0; r < 16; ++r) {
            const float s0 = sf0[r] * scale2 + mk0[r >> 2][r & 3] * LOG2E;
            const float s1 = sf1[r] * scale2 + mk1[r >> 2][r & 3] * LOG2E;
            sv0[r] = s0; sv1[r] = s1;
            mt[r] = fmaxf(s0, s1);
        }
        #pragma unroll
        for (int w = 8; w >= 1; w >>= 1)
            #pragma unroll
            for (int r = 0; r < w; ++r) mt[r] = fmaxf(mt[r], mt[r + w]);
        const float mx = fmaxf(mt[0], __shfl_xor(mt[0], 32, 64));

        // defer-max: rescale only when the max materially grows (p <= 2^8)
        const int upd = __any((int)(mx > m_run + 8.0f));
        float alpha;
        if (upd) {
            const float mnew = fmaxf(m_run, mx);
            alpha = __builtin_amdgcn_exp2f(m_run - mnew);
            m_run = mnew;
        }

        float ps[16];
        #pragma unroll
        for (int r = 0; r < 16; ++r) {
            sv0[r] = __builtin_amdgcn_exp2f(sv0[r] - m_run);
            sv1[r] = __builtin_amdgcn_exp2f(sv1[r] - m_run);
            ps[r] = sv0[r] + sv1[r];
        }
        #pragma unroll
        for (int w = 8; w >= 1; w >>= 1)
            #pragma unroll
            for (int r = 0; r < w; ++r) ps[r] += ps[r + w];
        const float pl = ps[0] + __shfl_xor(ps[0], 32, 64);

        if (upd) {
            l_run = l_run * alpha + pl;
            #pragma unroll
            for (int dt = 0; dt < 4; ++dt)
                #pragma unroll
                for (int r = 0; r < 16; ++r) oacc[dt][r] *= alpha;
        } else {
            l_run += pl;
        }

        // ---- P -> bf16 PV B-frags in-register (cvt_pk + permlane32_swap) ----
        // pf[s] holds P[q][kv = 16s + 8hi + j], j=0..7
        bf16x8 pf[4];
        #pragma unroll
        for (int s = 0; s < 4; ++s) {
            const int mlo4 = 4 * (2 * (s & 1));   // 4*mlo
            unsigned int a0, a1, b0, b1;
            const float e0 = (s < 2) ? sv0[mlo4 + 0] : sv1[mlo4 + 0];
            const float e1 = (s < 2) ? sv0[mlo4 + 1] : sv1[mlo4 + 1];
            const float e2 = (s < 2) ? sv0[mlo4 + 2] : sv1[mlo4 + 2];
            const float e3 = (s < 2) ? sv0[mlo4 + 3] : sv1[mlo4 + 3];
            const float e4 = (s < 2) ? sv0[mlo4 + 4] : sv1[mlo4 + 4];
            const float e5 = (s < 2) ? sv0[mlo4 + 5] : sv1[mlo4 + 5];
            const float e6 = (s < 2) ? sv0[mlo4 + 6] : sv1[mlo4 + 6];
            const float e7 = (s < 2) ? sv0[mlo4 + 7] : sv1[mlo4 + 7];
            asm("v_cvt_pk_bf16_f32 %0, %1, %2" : "=v"(a0) : "v"(e0), "v"(e1));
            asm("v_cvt_pk_bf16_f32 %0, %1, %2" : "=v"(a1) : "v"(e2), "v"(e3));
            asm("v_cvt_pk_bf16_f32 %0, %1, %2" : "=v"(b0) : "v"(e4), "v"(e5));
            asm("v_cvt_pk_bf16_f32 %0, %1, %2" : "=v"(b1) : "v"(e6), "v"(e7));
            // swap rows2,3 of dst with rows0,1 of src:
            //   a' = [a.low32 | b.low32] = j0..1 ; b' = [a.high32 | b.high32] = j4..5
            asm("v_permlane32_swap_b32 %0, %1" : "+v"(a0), "+v"(b0));
            asm("v_permlane32_swap_b32 %0, %1" : "+v"(a1), "+v"(b1));
            const u32x4 w = {a0, a1, b0, b1};
            pf[s] = __builtin_bit_cast(bf16x8, w);
        }

        asm volatile("s_waitcnt vmcnt(0)" ::: "memory");  // V[kt] DMA landed
        __syncthreads();

        // issue K[kt+1]; consumed next iteration (hidden by PV)
        const int nk = (kt + 1) & (NT - 1);
        #pragma unroll
        for (int p = 0; p < 4; ++p)
            gload16(ktiles + (size_t)nk * TILE_SH + p * 2048 + soff,
                    &k_lds[nk & 1][p * 2048 + loff]);

        // ---- O^T += V^T · P^T ----
        __builtin_amdgcn_s_setprio(1);
        #pragma unroll
        for (int dt = 0; dt < 4; ++dt) {
            #pragma unroll
            for (int s = 0; s < 4; ++s) {
                const bf16x8 vf = *(const bf16x8*)
                    &v_lds[vr + dt * 2048 + (((s * 2 + hi) ^ swV) << 3)];
                oacc[dt] = __builtin_amdgcn_mfma_f32_32x32x16_bf16(vf, pf[s], oacc[dt], 0, 0, 0);
            }
        }
        __builtin_amdgcn_s_setprio(0);
    }

    // ---- epilogue: normalize and store (per-lane scalar l) ----
    const float inv = 1.0f / l_run;
    float* orow = outg + (size_t)qrow_g * HD + hi * 4;
    #pragma unroll
    for (int dt = 0; dt < 4; ++dt)
        #pragma unroll
        for (int r = 0; r < 16; ++r)
            orow[dt * 32 + (r & 3) + 8 * (r >> 2)] = oacc[dt][r] * inv;
}

// ---------------------------------------------------------------------------
// Legacy kernel (round 3, proven) — fallback if workspace is too small.
// ---------------------------------------------------------------------------
#define KLD 136
#define VLD 72
#define PLD 68

__global__ __launch_bounds__(256, 2)
void fattn_legacy(const float* __restrict__ qg0, const float* __restrict__ kg0,
                  const float* __restrict__ vg0, const float* __restrict__ maskg,
                  float* __restrict__ outg0)
{
    __shared__ short k_lds[BK * KLD];
    __shared__ short vt_lds[HD * VLD];
    __shared__ short p_lds[4 * 16 * PLD];

    const int tid  = threadIdx.x;
    const int wave = tid >> 6;
    const int lane = tid & 63;
    const int quad = lane >> 4;
    const int l16  = lane & 15;

    const int bh = blockIdx.x;
    const int q0 = blockIdx.y * 64;

    const float* qg   = qg0 + (size_t)bh * S_LEN * HD;
    const float* kg   = kg0 + (size_t)bh * S_LEN * HD;
    const float* vg   = vg0 + (size_t)bh * S_LEN * HD;
    float*       outg = outg0 + (size_t)bh * S_LEN * HD;

    typedef __attribute__((ext_vector_type(4))) short s16x4l;

    bf16x8 qf[4];
    {
        const float* qrow = qg + (size_t)(q0 + wave * 16 + l16) * HD + quad * 8;
        #pragma unroll
        for (int ks = 0; ks < 4; ++ks) {
            const f32x4 a = *(const f32x4*)(qrow + ks * 32);
            const f32x4 b = *(const f32x4*)(qrow + ks * 32 + 4);
            #pragma unroll
            for (int j = 0; j < 4; ++j) {
                qf[ks][j]     = (short)f2bf(a[j]);
                qf[ks][j + 4] = (short)f2bf(b[j]);
            }
        }
    }

    float m_run[4], l_run[4];
    f32x4 oacc[8];
    #pragma unroll
    for (int r = 0; r < 4; ++r) { m_run[r] = -3.0e38f; l_run[r] = 0.0f; }
    #pragma unroll
    for (int d = 0; d < 8; ++d) oacc[d] = (f32x4){0.f, 0.f, 0.f, 0.f};

    const float scale = 0.088388347648318447f;
    const float* mrow = maskg + (size_t)(q0 + wave * 16 + quad * 4) * S_LEN + l16;

    const int rr = tid >> 5;
    const int cc = tid & 31;
    short* const pw = &p_lds[wave * 16 * PLD];

    f32x4 kpre[8], vpre[8];
    float mpre[4][4];
    #pragma unroll
    for (int it = 0; it < 8; ++it)
        kpre[it] = *(const f32x4*)(kg + (size_t)(rr + 8 * it) * HD + cc * 4);
    #pragma unroll
    for (int it = 0; it < 8; ++it)
        vpre[it] = *(const f32x4*)(vg + (size_t)(rr * 8 + it) * HD + cc * 4);
    #pragma unroll
    for (int nt = 0; nt < 4; ++nt)
        #pragma unroll
        for (int r = 0; r < 4; ++r)
            mpre[nt][r] = mrow[(size_t)r * S_LEN + nt * 16];

    for (int kt = 0; kt < NT; ++kt) {
        __syncthreads();

        #pragma unroll
        for (int it = 0; it < 8; ++it) {
            s16x4l kb4;
            kb4[0] = (short)f2bf(kpre[it][0]); kb4[1] = (short)f2bf(kpre[it][1]);
            kb4[2] = (short)f2bf(kpre[it][2]); kb4[3] = (short)f2bf(kpre[it][3]);
            *(s16x4l*)&k_lds[(rr + 8 * it) * KLD + cc * 4] = kb4;
        }
        #pragma unroll
        for (int i = 0; i < 4; ++i) {
            bf16x8 col;
            #pragma unroll
            for (int it = 0; it < 8; ++it)
                col[it] = (short)f2bf(vpre[it][i]);
            const int d = cc * 4 + i;
            const int pblk = rr ^ (cc & 7);
            *(bf16x8*)&vt_lds[d * VLD + pblk * 8] = col;
        }
        __syncthreads();

        const int nb = (kt + 1 < NT) ? (kt + 1) * BK : 0;
        #pragma unroll
        for (int it = 0; it < 8; ++it)
            kpre[it] = *(const f32x4*)(kg + (size_t)(nb + rr + 8 * it) * HD + cc * 4);
        #pragma unroll
        for (int it = 0; it < 8; ++it)
            vpre[it] = *(const f32x4*)(vg + (size_t)(nb + rr * 8 + it) * HD + cc * 4);

        f32x4 sf[4];
        #pragma unroll
        for (int nt = 0; nt < 4; ++nt) {
            f32x4 acc = (f32x4){0.f, 0.f, 0.f, 0.f};
            #pragma unroll
            for (int ks = 0; ks < 4; ++ks) {
                const bf16x8 kf =
                    *(const bf16x8*)&k_lds[(nt * 16 + l16) * KLD + ks * 32 + quad * 8];
                acc = __builtin_amdgcn_mfma_f32_16x16x32_bf16(qf[ks], kf, acc, 0, 0, 0);
            }
            sf[nt] = acc;
        }

        float sv[4][4];
        float mx[4] = {-3.0e38f, -3.0e38f, -3.0e38f, -3.0e38f};
        #pragma unroll
        for (int nt = 0; nt < 4; ++nt)
            #pragma unroll
            for (int r = 0; r < 4; ++r) {
                const float s = sf[nt][r] * scale + mpre[nt][r];
                sv[nt][r] = s;
                mx[r] = fmaxf(mx[r], s);
            }

        #pragma unroll
        for (int nt = 0; nt < 4; ++nt)
            #pragma unroll
            for (int r = 0; r < 4; ++r)
                mpre[nt][r] = mrow[(size_t)r * S_LEN + nb + nt * 16];

        #pragma unroll
        for (int r = 0; r < 4; ++r) {
            mx[r] = fmaxf(mx[r], __shfl_xor(mx[r], 1, 16));
            mx[r] = fmaxf(mx[r], __shfl_xor(mx[r], 2, 16));
            mx[r] = fmaxf(mx[r], __shfl_xor(mx[r], 4, 16));
            mx[r] = fmaxf(mx[r], __shfl_xor(mx[r], 8, 16));
        }

        float alpha[4], pl[4];
        #pragma unroll
        for (int r = 0; r < 4; ++r) {
            const float mnew = fmaxf(m_run[r], mx[r]);
            alpha[r] = __expf(m_run[r] - mnew);
            m_run[r] = mnew;
            pl[r] = 0.f;
        }

        short pb[4][4];
        #pragma unroll
        for (int nt = 0; nt < 4; ++nt)
            #pragma unroll
            for (int r = 0; r < 4; ++r) {
                const float p = __expf(sv[nt][r] - m_run[r]);
                const unsigned short b = f2bf(p);
                pb[nt][r] = (short)b;
                pl[r] += __builtin_bit_cast(float, (unsigned int)b << 16);
            }
        #pragma unroll
        for (int r = 0; r < 4; ++r) {
            pl[r] += __shfl_xor(pl[r], 1, 16);
            pl[r] += __shfl_xor(pl[r], 2, 16);
            pl[r] += __shfl_xor(pl[r], 4, 16);
            pl[r] += __shfl_xor(pl[r], 8, 16);
            l_run[r] = l_run[r] * alpha[r] + pl[r];
        }
        #pragma unroll
        for (int d = 0; d < 8; ++d)
            #pragma unroll
            for (int r = 0; r < 4; ++r)
                oacc[d][r] *= alpha[r];

        #pragma unroll
        for (int nt = 0; nt < 4; ++nt)
            #pragma unroll
            for (int r = 0; r < 4; ++r)
                pw[(quad * 4 + r) * PLD + nt * 16 + l16] = pb[nt][r];

        bf16x8 pf[2];
        #pragma unroll
        for (int ks = 0; ks < 2; ++ks) {
            const s16x4l lo = *(const s16x4l*)&pw[l16 * PLD + ks * 32 + quad * 8];
            const s16x4l hx = *(const s16x4l*)&pw[l16 * PLD + ks * 32 + quad * 8 + 4];
            pf[ks] = __builtin_shufflevector(lo, hx, 0, 1, 2, 3, 4, 5, 6, 7);
        }

        #pragma unroll
        for (int dt = 0; dt < 8; ++dt) {
            const int drow = dt * 16 + l16;
            const int tsw  = (drow >> 2) & 7;
            #pragma unroll
            for (int ks = 0; ks < 2; ++ks) {
                const bf16x8 vf =
                    *(const bf16x8*)&vt_lds[drow * VLD + (((4 * ks + quad) ^ tsw) * 8)];
                oacc[dt] = __builtin_amdgcn_mfma_f32_16x16x32_bf16(pf[ks], vf, oacc[dt], 0, 0, 0);
            }
        }
    }

    const int orow0 = q0 + wave * 16 + quad * 4;
    #pragma unroll
    for (int r = 0; r < 4; ++r) {
        const float inv = 1.0f / l_run[r];
        float* orow = outg + (size_t)(orow0 + r) * HD + l16;
        #pragma unroll
        for (int d = 0; d < 8; ++d)
            orow[d * 16] = oacc[d][r] * inv;
    }
}

extern "C" void kernel_launch(void* const* d_in, const int* in_sizes, int n_in,
                              void* d_out, int out_size, void* d_ws, size_t ws_size,
                              hipStream_t stream) {
    const float* q    = (const float*)d_in[0];
    const float* k    = (const float*)d_in[1];
    const float* v    = (const float*)d_in[2];
    const float* mask = (const float*)d_in[3];
    float* out = (float*)d_out;

    const size_t need = (size_t)2 * NBH * NT * TILE_SH * sizeof(short); // 64 MB
    if (d_ws != nullptr && ws_size >= need) {
        short* wsk = (short*)d_ws;
        short* wsv = wsk + (size_t)NBH * NT * TILE_SH;
        dim3 pgrid(NT, NBH, 2);
        prep_kernel<<<pgrid, 256, 0, stream>>>(k, v, wsk, wsv);
        dim3 grid(NBH, S_LEN / BQ);   // 4-wave blocks, BQ=128
        fattn_ws_kernel<<<grid, 256, 0, stream>>>(wsk, wsv, q, mask, out);
    } else {
        dim3 grid(NBH, S_LEN / 64);
        fattn_legacy<<<grid, 256, 0, stream>>>(q, k, v, mask, out);
    }
}